// Round 1
// baseline (286.237 us; speedup 1.0000x reference)
//
#include <hip/hip_runtime.h>

// Performer (FAVOR+) attention, MI355X bf16-MFMA implementation.
// Pipeline: cvt/transpose prep -> qkv GEMM -> per-head {phi_k,kv} -> reduce
//           -> per-head {phi_q, out, normalize} -> final GEMM (+bias).

typedef __attribute__((ext_vector_type(8))) short s8v;   // 8 x bf16 (4 VGPR)
typedef __attribute__((ext_vector_type(4))) short s4v;   // 4 x bf16
typedef __attribute__((ext_vector_type(4))) float f4v;   // MFMA acc
typedef __attribute__((ext_vector_type(4))) int   i4v;   // 16B chunk

#define MFMA16(a, b, c) __builtin_amdgcn_mfma_f32_16x16x32_bf16((a), (b), (c), 0, 0, 0)

__device__ __forceinline__ unsigned short f2bf(float f) {
  unsigned int u = __builtin_bit_cast(unsigned int, f);
  unsigned int r = (u + 0x7FFFu + ((u >> 16) & 1u)) >> 16;  // RNE
  return (unsigned short)r;
}

__device__ __forceinline__ void gl_lds16(const void* g, void* l) {
  __builtin_amdgcn_global_load_lds(
      (const __attribute__((address_space(1))) void*)g,
      (__attribute__((address_space(3))) void*)l, 16, 0, 0);
}

// ---------------------------------------------------------------- prep
__global__ __launch_bounds__(256) void cvt_bf16(const float* __restrict__ in,
                                                unsigned short* __restrict__ out,
                                                int n4) {
  int i = blockIdx.x * 256 + threadIdx.x;
  if (i >= n4) return;
  f4v v = ((const f4v*)in)[i];
  s4v o;
#pragma unroll
  for (int j = 0; j < 4; ++j) o[j] = (short)f2bf(v[j]);
  ((s4v*)out)[i] = o;
}

// out[z][c][r] = bf16(in[z][r][c]); R,C multiples of 32. block (32,8)
__global__ __launch_bounds__(256) void transpose_cvt(const float* __restrict__ in,
                                                     unsigned short* __restrict__ out,
                                                     int R, int C) {
  __shared__ float tile[32][33];
  const int tx = threadIdx.x, ty = threadIdx.y;
  const int z = blockIdx.z;
  const float* inz = in + (size_t)z * R * C;
  unsigned short* outz = out + (size_t)z * R * C;
  const int c0 = blockIdx.x * 32, r0 = blockIdx.y * 32;
#pragma unroll
  for (int j = 0; j < 4; ++j)
    tile[ty + j * 8][tx] = inz[(size_t)(r0 + ty + j * 8) * C + c0 + tx];
  __syncthreads();
#pragma unroll
  for (int j = 0; j < 4; ++j)
    outz[(size_t)(c0 + ty + j * 8) * R + r0 + tx] = f2bf(tile[tx][ty + j * 8]);
}

// ---------------------------------------------------------------- GEMM 128x128
// C[M,N] = A[M,K] @ Bt[N,K]^T ; A,Bt bf16.  MODE 0: bf16 out. MODE 1: f32 + bias.
template <int MODE>
__global__ __launch_bounds__(256) void gemm128(const unsigned short* __restrict__ A,
                                               const unsigned short* __restrict__ Bt,
                                               void* __restrict__ Cout,
                                               const float* __restrict__ bias,
                                               int M, int Nn, int K) {
  __shared__ unsigned short As[128 * 32];
  __shared__ unsigned short Bs[128 * 32];
  const int t = threadIdx.x, w = t >> 6, lane = t & 63;
  const int m0 = blockIdx.y * 128, n0 = blockIdx.x * 128;
  const int wr = w >> 1, wc = w & 1;
  const int fr = lane & 15, kg = (lane >> 4) * 8;
  const int sr = lane >> 2, sc = (lane & 3) * 8;

  f4v acc[4][4] = {};

  const int ra0 = (w * 2 + 0) * 16 + sr;
  const int ra1 = (w * 2 + 1) * 16 + sr;
  const unsigned short* gA0 = A + (size_t)(m0 + ra0) * K + sc;
  const unsigned short* gA1 = A + (size_t)(m0 + ra1) * K + sc;
  const unsigned short* gB0 = Bt + (size_t)(n0 + ra0) * K + sc;
  const unsigned short* gB1 = Bt + (size_t)(n0 + ra1) * K + sc;
  unsigned short* lA0 = &As[(w * 2 + 0) * 512];
  unsigned short* lA1 = &As[(w * 2 + 1) * 512];
  unsigned short* lB0 = &Bs[(w * 2 + 0) * 512];
  unsigned short* lB1 = &Bs[(w * 2 + 1) * 512];

  for (int k0 = 0; k0 < K; k0 += 32) {
    gl_lds16(gA0 + k0, lA0);
    gl_lds16(gA1 + k0, lA1);
    gl_lds16(gB0 + k0, lB0);
    gl_lds16(gB1 + k0, lB1);
    __syncthreads();
    s8v a[4], b[4];
#pragma unroll
    for (int m = 0; m < 4; ++m)
      a[m] = *(const s8v*)&As[(wr * 64 + m * 16 + fr) * 32 + kg];
#pragma unroll
    for (int n = 0; n < 4; ++n)
      b[n] = *(const s8v*)&Bs[(wc * 64 + n * 16 + fr) * 32 + kg];
#pragma unroll
    for (int m = 0; m < 4; ++m)
#pragma unroll
      for (int n = 0; n < 4; ++n)
        acc[m][n] = MFMA16(a[m], b[n], acc[m][n]);
    __syncthreads();
  }
#pragma unroll
  for (int m = 0; m < 4; ++m)
#pragma unroll
    for (int n = 0; n < 4; ++n) {
      const int row = m0 + wr * 64 + m * 16 + (lane >> 4) * 4;
      const int col = n0 + wc * 64 + n * 16 + fr;
      if (MODE == 0) {
        unsigned short* C = (unsigned short*)Cout;
#pragma unroll
        for (int r = 0; r < 4; ++r)
          C[(size_t)(row + r) * Nn + col] = f2bf(acc[m][n][r]);
      } else {
        float* C = (float*)Cout;
        const float bv = bias[col];
#pragma unroll
        for (int r = 0; r < 4; ++r)
          C[(size_t)(row + r) * Nn + col] = acc[m][n][r] + bv;
      }
    }
}

// ---------------------------------------------------------------- phi_k + kv
// block = (och, h, b); processes 512 tokens in 4 chunks of 128.
// kvpart[bh][och][80][64]: rows 0..63 = kv^T (d,r), row 64 = k_sum, 65..79 = 0.
__global__ __launch_bounds__(256) void phik_kv(const unsigned short* __restrict__ qkv,
                                               const unsigned short* __restrict__ RFt,
                                               float* __restrict__ kvpart) {
  __shared__ unsigned short RFl[2 * 64 * 32];   // [p][r][32]
  __shared__ unsigned short Kl[2 * 128 * 32];   // [p][n][32]
  __shared__ unsigned short pht[64 * 136];      // [r][n] (+pad)
  __shared__ unsigned short vt[80 * 136];       // [d][n] (+ones row 64)
  const int t = threadIdx.x, w = t >> 6, lane = t & 63;
  const int och = blockIdx.x, h = blockIdx.y, b = blockIdx.z;
  const int fr = lane & 15, kg = (lane >> 4) * 8;

#pragma unroll
  for (int i = 0; i < 2; ++i) {  // RF[h] -> RFl
    int unit = i * 256 + w * 64 + lane;
    int p = unit >> 8, rem = unit & 255;
    int r = rem >> 2, cg = (rem & 3) * 8;
    gl_lds16(RFt + ((h * 64 + r) * 64 + p * 32 + cg), &RFl[(i * 256 + w * 64) * 8]);
  }
  for (int i = t; i < 136; i += 256) vt[64 * 136 + i] = 0x3F80;     // ones row
  for (int i = t; i < 15 * 136; i += 256) vt[65 * 136 + i] = 0;     // zero pad rows

  f4v kvacc[5] = {};

  for (int c = 0; c < 4; ++c) {
    const int n0c = och * 512 + c * 128;
    const size_t rowbase = (size_t)(b * 4096 + n0c);
#pragma unroll
    for (int i = 0; i < 4; ++i) {  // K slice -> Kl
      int unit = i * 256 + w * 64 + lane;
      int p = unit >> 9, rem = unit & 511;
      int n = rem >> 2, cg = (rem & 3) * 8;
      gl_lds16(qkv + (rowbase + n) * 3072 + 1024 + h * 64 + p * 32 + cg,
               &Kl[(i * 256 + w * 64) * 8]);
    }
    i4v vreg[4];
#pragma unroll
    for (int it = 0; it < 4; ++it) {  // V slice -> regs
      int slot = it * 256 + t;
      vreg[it] = *(const i4v*)&qkv[(rowbase + (slot >> 3)) * 3072 + 2048 + h * 64 +
                                   (slot & 7) * 8];
    }
    __syncthreads();
    // phi_k = relu(K @ RF)
    f4v pacc[2][4] = {};
#pragma unroll
    for (int p = 0; p < 2; ++p) {
      s8v ka[2], rb[4];
#pragma unroll
      for (int m = 0; m < 2; ++m)
        ka[m] = *(const s8v*)&Kl[p * 4096 + (w * 32 + m * 16 + fr) * 32 + kg];
#pragma unroll
      for (int rf = 0; rf < 4; ++rf)
        rb[rf] = *(const s8v*)&RFl[p * 2048 + (rf * 16 + fr) * 32 + kg];
#pragma unroll
      for (int m = 0; m < 2; ++m)
#pragma unroll
        for (int rf = 0; rf < 4; ++rf)
          pacc[m][rf] = MFMA16(ka[m], rb[rf], pacc[m][rf]);
    }
    // v -> vt (transposed)
#pragma unroll
    for (int it = 0; it < 4; ++it) {
      int slot = it * 256 + t;
      int vn = slot >> 3, vdh = (slot & 7) * 8;
      const unsigned short* vr = (const unsigned short*)&vreg[it];
#pragma unroll
      for (int j = 0; j < 8; ++j) vt[(vdh + j) * 136 + vn] = vr[j];
    }
    // phi -> pht (transposed, relu, bf16)
#pragma unroll
    for (int m = 0; m < 2; ++m)
#pragma unroll
      for (int rf = 0; rf < 4; ++rf) {
        int r = rf * 16 + fr;
        int nb = w * 32 + m * 16 + (lane >> 4) * 4;
        s4v pk;
#pragma unroll
        for (int g = 0; g < 4; ++g) pk[g] = (short)f2bf(fmaxf(pacc[m][rf][g], 0.0f));
        *(s4v*)&pht[r * 136 + nb] = pk;
      }
    __syncthreads();
    // kv_aug[d][r] += vt @ pht^T  (wave w owns r-cols w*16..+15)
#pragma unroll
    for (int kst = 0; kst < 4; ++kst) {
      s8v pb = *(const s8v*)&pht[(w * 16 + fr) * 136 + kst * 32 + kg];
#pragma unroll
      for (int f = 0; f < 5; ++f) {
        s8v va = *(const s8v*)&vt[(f * 16 + fr) * 136 + kst * 32 + kg];
        kvacc[f] = MFMA16(va, pb, kvacc[f]);
      }
    }
  }
  const int bh = b * 16 + h;
  float* outp = kvpart + ((size_t)bh * 8 + och) * (80 * 64);
#pragma unroll
  for (int f = 0; f < 5; ++f) {
    int row = f * 16 + (lane >> 4) * 4;
    int col = w * 16 + fr;
#pragma unroll
    for (int g = 0; g < 4; ++g) outp[(row + g) * 64 + col] = kvacc[f][g];
  }
}

__global__ __launch_bounds__(256) void kv_reduce(const float* __restrict__ kvpart,
                                                 unsigned short* __restrict__ kvt) {
  const int bh = blockIdx.x, t = threadIdx.x;
  for (int i = t; i < 80 * 64; i += 256) {
    float s = 0.f;
#pragma unroll
    for (int c = 0; c < 8; ++c) s += kvpart[((size_t)bh * 8 + c) * 5120 + i];
    kvt[(size_t)bh * 5120 + i] = f2bf(s);
  }
}

// ---------------------------------------------------------------- phi_q + out
// block = (ch, h, b); 128 tokens. attno[token][h*64+d] = (phi_q@kv)/(phi_q.k_sum+eps)
__global__ __launch_bounds__(256) void phiq_out(const unsigned short* __restrict__ qkv,
                                                const unsigned short* __restrict__ RFt,
                                                const unsigned short* __restrict__ kvt,
                                                unsigned short* __restrict__ attno) {
  __shared__ unsigned short RFl[2 * 64 * 32];  // [p][r][32]
  __shared__ unsigned short Ql[2 * 128 * 32];  // [p][n][32]
  __shared__ unsigned short phl[128 * 72];     // [n][r] (+pad)
  __shared__ unsigned short kvl[80 * 72];      // [d][r] (+pad), row 64 = k_sum
  const int t = threadIdx.x, w = t >> 6, lane = t & 63;
  const int ch = blockIdx.x, h = blockIdx.y, b = blockIdx.z;
  const int fr = lane & 15, kg = (lane >> 4) * 8;
  const int bh = b * 16 + h;
  const size_t rowbase = (size_t)(b * 4096 + ch * 128);

#pragma unroll
  for (int i = 0; i < 2; ++i) {
    int unit = i * 256 + w * 64 + lane;
    int p = unit >> 8, rem = unit & 255;
    int r = rem >> 2, cg = (rem & 3) * 8;
    gl_lds16(RFt + ((h * 64 + r) * 64 + p * 32 + cg), &RFl[(i * 256 + w * 64) * 8]);
  }
#pragma unroll
  for (int i = 0; i < 4; ++i) {
    int unit = i * 256 + w * 64 + lane;
    int p = unit >> 9, rem = unit & 511;
    int n = rem >> 2, cg = (rem & 3) * 8;
    gl_lds16(qkv + (rowbase + n) * 3072 + h * 64 + p * 32 + cg,
             &Ql[(i * 256 + w * 64) * 8]);
  }
  for (int i = t; i < 640; i += 256) {  // kvt -> kvl (pad 64->72)
    int row = i >> 3, cg = (i & 7) * 8;
    *(i4v*)&kvl[row * 72 + cg] = *(const i4v*)&kvt[(size_t)bh * 5120 + row * 64 + cg];
  }
  __syncthreads();
  f4v pacc[2][4] = {};
#pragma unroll
  for (int p = 0; p < 2; ++p) {
    s8v qa[2], rb[4];
#pragma unroll
    for (int m = 0; m < 2; ++m)
      qa[m] = *(const s8v*)&Ql[p * 4096 + (w * 32 + m * 16 + fr) * 32 + kg];
#pragma unroll
    for (int rf = 0; rf < 4; ++rf)
      rb[rf] = *(const s8v*)&RFl[p * 2048 + (rf * 16 + fr) * 32 + kg];
#pragma unroll
    for (int m = 0; m < 2; ++m)
#pragma unroll
      for (int rf = 0; rf < 4; ++rf)
        pacc[m][rf] = MFMA16(qa[m], rb[rf], pacc[m][rf]);
  }
#pragma unroll
  for (int m = 0; m < 2; ++m)
#pragma unroll
    for (int rf = 0; rf < 4; ++rf) {
      int r = rf * 16 + fr;
      int nb = w * 32 + m * 16 + (lane >> 4) * 4;
#pragma unroll
      for (int g = 0; g < 4; ++g)
        phl[(nb + g) * 72 + r] = f2bf(fmaxf(pacc[m][rf][g], 0.0f));
    }
  __syncthreads();
  f4v acc[2][5] = {};
#pragma unroll
  for (int kst = 0; kst < 2; ++kst) {
    s8v pa[2], kb[5];
#pragma unroll
    for (int m = 0; m < 2; ++m)
      pa[m] = *(const s8v*)&phl[(w * 32 + m * 16 + fr) * 72 + kst * 32 + kg];
#pragma unroll
    for (int f = 0; f < 5; ++f)
      kb[f] = *(const s8v*)&kvl[(f * 16 + fr) * 72 + kst * 32 + kg];
#pragma unroll
    for (int m = 0; m < 2; ++m)
#pragma unroll
      for (int f = 0; f < 5; ++f) acc[m][f] = MFMA16(pa[m], kb[f], acc[m][f]);
  }
#pragma unroll
  for (int m = 0; m < 2; ++m)
#pragma unroll
    for (int g = 0; g < 4; ++g) {
      float nrm = __shfl(acc[m][4][g], lane & 48) + 1e-6f;  // col 64 = phi_q.k_sum
      int n = w * 32 + m * 16 + (lane >> 4) * 4 + g;
      size_t orow = rowbase + n;
#pragma unroll
      for (int f = 0; f < 4; ++f)
        attno[orow * 1024 + h * 64 + f * 16 + fr] = f2bf(acc[m][f][g] / nrm);
    }
}

// ---------------------------------------------------------------- launch
extern "C" void kernel_launch(void* const* d_in, const int* in_sizes, int n_in,
                              void* d_out, int out_size, void* d_ws, size_t ws_size,
                              hipStream_t stream) {
  const float* x = (const float*)d_in[0];      // [4,4096,1024]
  const float* W_qkv = (const float*)d_in[1];  // [1024,3072]
  const float* RF = (const float*)d_in[2];     // [16,64,64]
  const float* W_out = (const float*)d_in[3];  // [1024,1024]
  const float* b_out = (const float*)d_in[4];  // [1024]
  float* out = (float*)d_out;                  // [4,4096,1024]

  char* ws = (char*)d_ws;
  size_t off = 0;
  auto alloc = [&](size_t bytes) -> void* {
    void* p = ws + off;
    off += (bytes + 255) & ~(size_t)255;
    return p;
  };
  unsigned short* xb = (unsigned short*)alloc(16384ull * 1024 * 2);
  unsigned short* wqkvt = (unsigned short*)alloc(3072ull * 1024 * 2);
  unsigned short* woutt = (unsigned short*)alloc(1024ull * 1024 * 2);
  unsigned short* rft = (unsigned short*)alloc(16ull * 64 * 64 * 2);
  unsigned short* qkv = (unsigned short*)alloc(16384ull * 3072 * 2);
  float* kvpart = (float*)alloc(64ull * 8 * 80 * 64 * 4);
  unsigned short* kvt = (unsigned short*)alloc(64ull * 80 * 64 * 2);
  unsigned short* attno = (unsigned short*)alloc(16384ull * 1024 * 2);

  cvt_bf16<<<16384, 256, 0, stream>>>(x, xb, 4194304);
  transpose_cvt<<<dim3(96, 32, 1), dim3(32, 8), 0, stream>>>(W_qkv, wqkvt, 1024, 3072);
  transpose_cvt<<<dim3(32, 32, 1), dim3(32, 8), 0, stream>>>(W_out, woutt, 1024, 1024);
  transpose_cvt<<<dim3(2, 2, 16), dim3(32, 8), 0, stream>>>(RF, rft, 64, 64);

  gemm128<0><<<dim3(24, 128), 256, 0, stream>>>(xb, wqkvt, qkv, nullptr, 16384, 3072, 1024);
  phik_kv<<<dim3(8, 16, 4), 256, 0, stream>>>(qkv, rft, kvpart);
  kv_reduce<<<64, 256, 0, stream>>>(kvpart, kvt);
  phiq_out<<<dim3(32, 16, 4), 256, 0, stream>>>(qkv, rft, kvt, attno);
  gemm128<1><<<dim3(8, 128), 256, 0, stream>>>(attno, woutt, out, b_out, 16384, 1024, 1024);
}

// Round 2
// 241.173 us; speedup vs baseline: 1.1868x; 1.1868x over previous
//
#include <hip/hip_runtime.h>

// Performer (FAVOR+) attention, MI355X bf16-MFMA implementation.
// Round 2: both big GEMMs upgraded to 256x256 8-phase template
// (T1 XCD swizzle + T2 LDS XOR swizzle + T3/T4 counted vmcnt + T5 setprio).

typedef __attribute__((ext_vector_type(8))) short s8v;   // 8 x bf16 (4 VGPR)
typedef __attribute__((ext_vector_type(4))) short s4v;   // 4 x bf16
typedef __attribute__((ext_vector_type(4))) float f4v;   // MFMA acc
typedef __attribute__((ext_vector_type(4))) int   i4v;   // 16B chunk

#define MFMA16(a, b, c) __builtin_amdgcn_mfma_f32_16x16x32_bf16((a), (b), (c), 0, 0, 0)

__device__ __forceinline__ unsigned short f2bf(float f) {
  unsigned int u = __builtin_bit_cast(unsigned int, f);
  unsigned int r = (u + 0x7FFFu + ((u >> 16) & 1u)) >> 16;  // RNE
  return (unsigned short)r;
}

__device__ __forceinline__ void gl_lds16(const void* g, void* l) {
  __builtin_amdgcn_global_load_lds(
      (const __attribute__((address_space(1))) void*)g,
      (__attribute__((address_space(3))) void*)l, 16, 0, 0);
}

// ---------------------------------------------------------------- prep
__global__ __launch_bounds__(256) void cvt_bf16(const float* __restrict__ in,
                                                unsigned short* __restrict__ out,
                                                int n4) {
  int i = blockIdx.x * 256 + threadIdx.x;
  if (i >= n4) return;
  f4v v = ((const f4v*)in)[i];
  s4v o;
#pragma unroll
  for (int j = 0; j < 4; ++j) o[j] = (short)f2bf(v[j]);
  ((s4v*)out)[i] = o;
}

// out[z][c][r] = bf16(in[z][r][c]); R,C multiples of 32. block (32,8)
__global__ __launch_bounds__(256) void transpose_cvt(const float* __restrict__ in,
                                                     unsigned short* __restrict__ out,
                                                     int R, int C) {
  __shared__ float tile[32][33];
  const int tx = threadIdx.x, ty = threadIdx.y;
  const int z = blockIdx.z;
  const float* inz = in + (size_t)z * R * C;
  unsigned short* outz = out + (size_t)z * R * C;
  const int c0 = blockIdx.x * 32, r0 = blockIdx.y * 32;
#pragma unroll
  for (int j = 0; j < 4; ++j)
    tile[ty + j * 8][tx] = inz[(size_t)(r0 + ty + j * 8) * C + c0 + tx];
  __syncthreads();
#pragma unroll
  for (int j = 0; j < 4; ++j)
    outz[(size_t)(c0 + ty + j * 8) * R + r0 + tx] = f2bf(tile[tx][ty + j * 8]);
}

// ---------------------------------------------------------------- GEMM 256x256
// C[M,N] = A[M,K] @ Bt[N,K]^T.  8-phase schedule, BK=64, 512 threads (8 waves,
// 2Mx4N), 128 KiB LDS = 2 dbuf x {A,B} x 2 halves x [128 rows][64 cols] bf16.
// LDS swizzle: byte a -> a ^ (((a>>8)&3)<<4)  (row bits 1,2 into 16B-chunk bits),
// applied as inverse-swizzled GLOBAL source (linear global_load_lds dest) and
// swizzled ds_read address (rule 21: same involution both sides).
// Phases per K-tile T (quadrant (mh,nh)): q0=(0,0) reads A-mh0+B-nh0,
// q1=(0,1) reads B-nh1 (A reused), q2=(1,1) reads A-mh1 (B reused), q3=(1,0)
// reads nothing. Stage sequence: half H=4T+5+q at phase q (H: tile H>>2,
// part H&3: 0,1=A halves, 2,3=B halves). Every region's last LDS read is >=2
// barriers before its restage (barrier-safe WAR). vmcnt(2) at q3 guarantees
// tile T+1 landed before its first read (vmcnt(0) at T=nkt-2 drains the tail).
template <int MODE>
__global__ __launch_bounds__(512, 2) void gemm256(const unsigned short* __restrict__ A,
                                                  const unsigned short* __restrict__ Bt,
                                                  void* __restrict__ Cout,
                                                  const float* __restrict__ bias,
                                                  int Nn, int K, int NTN, int CPX) {
  __shared__ __align__(128) unsigned short smem[65536];  // 128 KiB
  const int t = threadIdx.x, w = t >> 6, lane = t & 63;
  const int wm = w >> 2, wn = w & 3;
  const int fr = lane & 15, c16 = (lane >> 4) * 16;
  const int nkt = K >> 6;

  // T1: XCD-bijective block swizzle (grid % 8 == 0)
  const int bid = blockIdx.x;
  const int wg = (bid & 7) * CPX + (bid >> 3);
  const int tm = wg / NTN, tn = wg % NTN;

  const unsigned short* gA = A + (size_t)tm * 256 * K;
  const unsigned short* gB = Bt + (size_t)tn * 256 * K;

  // per-thread pre-swizzled global source offsets for the 2 staging loads
  const int a0 = t * 16, a1 = 8192 + t * 16;
  const int s0 = a0 ^ (((a0 >> 8) & 3) << 4);
  const int s1 = a1 ^ (((a1 >> 8) & 3) << 4);
  const int goff0 = (s0 >> 7) * K + ((s0 & 127) >> 1);
  const int goff1 = (s1 >> 7) * K + ((s1 & 127) >> 1);
  const int woff = w * 1024;  // wave-uniform LDS byte offset

  auto stage = [&](int H) {
    if (H >= nkt * 4) return;
    const int TH = H >> 2, part = H & 3;
    char* reg = (char*)smem + (((TH & 1) * 4 + part) << 14);
    const unsigned short* gp =
        (part < 2 ? gA : gB) + (size_t)((part & 1) * 128) * K + TH * 64;
    gl_lds16(gp + goff0, reg + woff);
    gl_lds16(gp + goff1, reg + 8192 + woff);
  };

  f4v acc[8][4] = {};

  // prologue: halves 0..4 (tile0 + tile1.A0), drain to 2 loads, barrier
#pragma unroll
  for (int H = 0; H < 5; ++H) stage(H);
  if (nkt > 1) { asm volatile("s_waitcnt vmcnt(2)" ::: "memory"); }
  else         { asm volatile("s_waitcnt vmcnt(0)" ::: "memory"); }
  __builtin_amdgcn_s_barrier();
  __builtin_amdgcn_sched_barrier(0);

  auto rdA = [&](int mh, s8v (&a)[4][2], const char* Ar) {
#pragma unroll
    for (int i = 0; i < 4; ++i)
#pragma unroll
      for (int ks = 0; ks < 2; ++ks) {
        int p = (mh * 64 + i * 16 + fr) * 128 + ks * 64 + c16;
        p ^= ((p >> 8) & 3) << 4;
        a[i][ks] = *(const s8v*)(Ar + p);
      }
  };
  auto rdB = [&](int nh, s8v (&b)[2][2], const char* Br, int brow) {
#pragma unroll
    for (int j = 0; j < 2; ++j)
#pragma unroll
      for (int ks = 0; ks < 2; ++ks) {
        int p = (brow + nh * 32 + j * 16 + fr) * 128 + ks * 64 + c16;
        p ^= ((p >> 8) & 3) << 4;
        b[j][ks] = *(const s8v*)(Br + p);
      }
  };
  auto mmac = [&](int mh, int nh, const s8v (&a)[4][2], const s8v (&b)[2][2]) {
    __builtin_amdgcn_s_setprio(1);
#pragma unroll
    for (int i = 0; i < 4; ++i)
#pragma unroll
      for (int j = 0; j < 2; ++j) {
        acc[mh * 4 + i][nh * 2 + j] = MFMA16(a[i][0], b[j][0], acc[mh * 4 + i][nh * 2 + j]);
        acc[mh * 4 + i][nh * 2 + j] = MFMA16(a[i][1], b[j][1], acc[mh * 4 + i][nh * 2 + j]);
      }
    __builtin_amdgcn_s_setprio(0);
  };

  const int brow = (wn & 1) * 64;
  for (int T = 0; T < nkt; ++T) {
    const int d = T & 1;
    const char* Ar = (const char*)smem + ((d * 4 + wm) << 14);
    const char* Br = (const char*)smem + ((d * 4 + 2 + (wn >> 1)) << 14);
    s8v a[4][2], b0[2][2], b1[2][2];
    // q0: quadrant (0,0)
    rdA(0, a, Ar); rdB(0, b0, Br, brow); stage(4 * T + 5);
    __builtin_amdgcn_s_barrier();
    mmac(0, 0, a, b0);
    __builtin_amdgcn_s_barrier();
    __builtin_amdgcn_sched_barrier(0);
    // q1: quadrant (0,1) — reuse A
    rdB(1, b1, Br, brow); stage(4 * T + 6);
    __builtin_amdgcn_s_barrier();
    mmac(0, 1, a, b1);
    __builtin_amdgcn_s_barrier();
    __builtin_amdgcn_sched_barrier(0);
    // q2: quadrant (1,1) — reuse B1
    rdA(1, a, Ar); stage(4 * T + 7);
    __builtin_amdgcn_s_barrier();
    mmac(1, 1, a, b1);
    __builtin_amdgcn_s_barrier();
    __builtin_amdgcn_sched_barrier(0);
    // q3: quadrant (1,0) — no reads; counted wait for tile T+1
    stage(4 * T + 8);
    if (T < nkt - 2)       { asm volatile("s_waitcnt vmcnt(2)" ::: "memory"); }
    else if (T == nkt - 2) { asm volatile("s_waitcnt vmcnt(0)" ::: "memory"); }
    __builtin_amdgcn_s_barrier();
    mmac(1, 0, a, b0);
    __builtin_amdgcn_s_barrier();
    __builtin_amdgcn_sched_barrier(0);
  }

  // epilogue
#pragma unroll
  for (int m = 0; m < 8; ++m)
#pragma unroll
    for (int n = 0; n < 4; ++n) {
      const int row = tm * 256 + wm * 128 + m * 16 + (lane >> 4) * 4;
      const int col = tn * 256 + wn * 64 + n * 16 + fr;
      if (MODE == 0) {
        unsigned short* C = (unsigned short*)Cout;
#pragma unroll
        for (int r = 0; r < 4; ++r)
          C[(size_t)(row + r) * Nn + col] = f2bf(acc[m][n][r]);
      } else {
        float* C = (float*)Cout;
        const float bv = bias[col];
#pragma unroll
        for (int r = 0; r < 4; ++r)
          C[(size_t)(row + r) * Nn + col] = acc[m][n][r] + bv;
      }
    }
}

// ---------------------------------------------------------------- phi_k + kv
// block = (och, h, b); processes 512 tokens in 4 chunks of 128.
// kvpart[bh][och][80][64]: rows 0..63 = kv^T (d,r), row 64 = k_sum, 65..79 = 0.
__global__ __launch_bounds__(256) void phik_kv(const unsigned short* __restrict__ qkv,
                                               const unsigned short* __restrict__ RFt,
                                               float* __restrict__ kvpart) {
  __shared__ unsigned short RFl[2 * 64 * 32];   // [p][r][32]
  __shared__ unsigned short Kl[2 * 128 * 32];   // [p][n][32]
  __shared__ unsigned short pht[64 * 136];      // [r][n] (+pad)
  __shared__ unsigned short vt[80 * 136];       // [d][n] (+ones row 64)
  const int t = threadIdx.x, w = t >> 6, lane = t & 63;
  const int och = blockIdx.x, h = blockIdx.y, b = blockIdx.z;
  const int fr = lane & 15, kg = (lane >> 4) * 8;

#pragma unroll
  for (int i = 0; i < 2; ++i) {  // RF[h] -> RFl
    int unit = i * 256 + w * 64 + lane;
    int p = unit >> 8, rem = unit & 255;
    int r = rem >> 2, cg = (rem & 3) * 8;
    gl_lds16(RFt + ((h * 64 + r) * 64 + p * 32 + cg), &RFl[(i * 256 + w * 64) * 8]);
  }
  for (int i = t; i < 136; i += 256) vt[64 * 136 + i] = 0x3F80;     // ones row
  for (int i = t; i < 15 * 136; i += 256) vt[65 * 136 + i] = 0;     // zero pad rows

  f4v kvacc[5] = {};

  for (int c = 0; c < 4; ++c) {
    const int n0c = och * 512 + c * 128;
    const size_t rowbase = (size_t)(b * 4096 + n0c);
#pragma unroll
    for (int i = 0; i < 4; ++i) {  // K slice -> Kl
      int unit = i * 256 + w * 64 + lane;
      int p = unit >> 9, rem = unit & 511;
      int n = rem >> 2, cg = (rem & 3) * 8;
      gl_lds16(qkv + (rowbase + n) * 3072 + 1024 + h * 64 + p * 32 + cg,
               &Kl[(i * 256 + w * 64) * 8]);
    }
    i4v vreg[4];
#pragma unroll
    for (int it = 0; it < 4; ++it) {  // V slice -> regs
      int slot = it * 256 + t;
      vreg[it] = *(const i4v*)&qkv[(rowbase + (slot >> 3)) * 3072 + 2048 + h * 64 +
                                   (slot & 7) * 8];
    }
    __syncthreads();
    // phi_k = relu(K @ RF)
    f4v pacc[2][4] = {};
#pragma unroll
    for (int p = 0; p < 2; ++p) {
      s8v ka[2], rb[4];
#pragma unroll
      for (int m = 0; m < 2; ++m)
        ka[m] = *(const s8v*)&Kl[p * 4096 + (w * 32 + m * 16 + fr) * 32 + kg];
#pragma unroll
      for (int rf = 0; rf < 4; ++rf)
        rb[rf] = *(const s8v*)&RFl[p * 2048 + (rf * 16 + fr) * 32 + kg];
#pragma unroll
      for (int m = 0; m < 2; ++m)
#pragma unroll
        for (int rf = 0; rf < 4; ++rf)
          pacc[m][rf] = MFMA16(ka[m], rb[rf], pacc[m][rf]);
    }
    // v -> vt (transposed)
#pragma unroll
    for (int it = 0; it < 4; ++it) {
      int slot = it * 256 + t;
      int vn = slot >> 3, vdh = (slot & 7) * 8;
      const unsigned short* vr = (const unsigned short*)&vreg[it];
#pragma unroll
      for (int j = 0; j < 8; ++j) vt[(vdh + j) * 136 + vn] = vr[j];
    }
    // phi -> pht (transposed, relu, bf16)
#pragma unroll
    for (int m = 0; m < 2; ++m)
#pragma unroll
      for (int rf = 0; rf < 4; ++rf) {
        int r = rf * 16 + fr;
        int nb = w * 32 + m * 16 + (lane >> 4) * 4;
        s4v pk;
#pragma unroll
        for (int g = 0; g < 4; ++g) pk[g] = (short)f2bf(fmaxf(pacc[m][rf][g], 0.0f));
        *(s4v*)&pht[r * 136 + nb] = pk;
      }
    __syncthreads();
    // kv_aug[d][r] += vt @ pht^T  (wave w owns r-cols w*16..+15)
#pragma unroll
    for (int kst = 0; kst < 4; ++kst) {
      s8v pb = *(const s8v*)&pht[(w * 16 + fr) * 136 + kst * 32 + kg];
#pragma unroll
      for (int f = 0; f < 5; ++f) {
        s8v va = *(const s8v*)&vt[(f * 16 + fr) * 136 + kst * 32 + kg];
        kvacc[f] = MFMA16(va, pb, kvacc[f]);
      }
    }
  }
  const int bh = b * 16 + h;
  float* outp = kvpart + ((size_t)bh * 8 + och) * (80 * 64);
#pragma unroll
  for (int f = 0; f < 5; ++f) {
    int row = f * 16 + (lane >> 4) * 4;
    int col = w * 16 + fr;
#pragma unroll
    for (int g = 0; g < 4; ++g) outp[(row + g) * 64 + col] = kvacc[f][g];
  }
}

__global__ __launch_bounds__(256) void kv_reduce(const float* __restrict__ kvpart,
                                                 unsigned short* __restrict__ kvt) {
  const int bh = blockIdx.x, t = threadIdx.x;
  for (int i = t; i < 80 * 64; i += 256) {
    float s = 0.f;
#pragma unroll
    for (int c = 0; c < 8; ++c) s += kvpart[((size_t)bh * 8 + c) * 5120 + i];
    kvt[(size_t)bh * 5120 + i] = f2bf(s);
  }
}

// ---------------------------------------------------------------- phi_q + out
// block = (ch, h, b); 128 tokens. attno[token][h*64+d] = (phi_q@kv)/(phi_q.k_sum+eps)
__global__ __launch_bounds__(256) void phiq_out(const unsigned short* __restrict__ qkv,
                                                const unsigned short* __restrict__ RFt,
                                                const unsigned short* __restrict__ kvt,
                                                unsigned short* __restrict__ attno) {
  __shared__ unsigned short RFl[2 * 64 * 32];  // [p][r][32]
  __shared__ unsigned short Ql[2 * 128 * 32];  // [p][n][32]
  __shared__ unsigned short phl[128 * 72];     // [n][r] (+pad)
  __shared__ unsigned short kvl[80 * 72];      // [d][r] (+pad), row 64 = k_sum
  const int t = threadIdx.x, w = t >> 6, lane = t & 63;
  const int ch = blockIdx.x, h = blockIdx.y, b = blockIdx.z;
  const int fr = lane & 15, kg = (lane >> 4) * 8;
  const int bh = b * 16 + h;
  const size_t rowbase = (size_t)(b * 4096 + ch * 128);

#pragma unroll
  for (int i = 0; i < 2; ++i) {
    int unit = i * 256 + w * 64 + lane;
    int p = unit >> 8, rem = unit & 255;
    int r = rem >> 2, cg = (rem & 3) * 8;
    gl_lds16(RFt + ((h * 64 + r) * 64 + p * 32 + cg), &RFl[(i * 256 + w * 64) * 8]);
  }
#pragma unroll
  for (int i = 0; i < 4; ++i) {
    int unit = i * 256 + w * 64 + lane;
    int p = unit >> 9, rem = unit & 511;
    int n = rem >> 2, cg = (rem & 3) * 8;
    gl_lds16(qkv + (rowbase + n) * 3072 + h * 64 + p * 32 + cg,
             &Ql[(i * 256 + w * 64) * 8]);
  }
  for (int i = t; i < 640; i += 256) {  // kvt -> kvl (pad 64->72)
    int row = i >> 3, cg = (i & 7) * 8;
    *(i4v*)&kvl[row * 72 + cg] = *(const i4v*)&kvt[(size_t)bh * 5120 + row * 64 + cg];
  }
  __syncthreads();
  f4v pacc[2][4] = {};
#pragma unroll
  for (int p = 0; p < 2; ++p) {
    s8v qa[2], rb[4];
#pragma unroll
    for (int m = 0; m < 2; ++m)
      qa[m] = *(const s8v*)&Ql[p * 4096 + (w * 32 + m * 16 + fr) * 32 + kg];
#pragma unroll
    for (int rf = 0; rf < 4; ++rf)
      rb[rf] = *(const s8v*)&RFl[p * 2048 + (rf * 16 + fr) * 32 + kg];
#pragma unroll
    for (int m = 0; m < 2; ++m)
#pragma unroll
      for (int rf = 0; rf < 4; ++rf)
        pacc[m][rf] = MFMA16(qa[m], rb[rf], pacc[m][rf]);
  }
#pragma unroll
  for (int m = 0; m < 2; ++m)
#pragma unroll
    for (int rf = 0; rf < 4; ++rf) {
      int r = rf * 16 + fr;
      int nb = w * 32 + m * 16 + (lane >> 4) * 4;
#pragma unroll
      for (int g = 0; g < 4; ++g)
        phl[(nb + g) * 72 + r] = f2bf(fmaxf(pacc[m][rf][g], 0.0f));
    }
  __syncthreads();
  f4v acc[2][5] = {};
#pragma unroll
  for (int kst = 0; kst < 2; ++kst) {
    s8v pa[2], kb[5];
#pragma unroll
    for (int m = 0; m < 2; ++m)
      pa[m] = *(const s8v*)&phl[(w * 32 + m * 16 + fr) * 72 + kst * 32 + kg];
#pragma unroll
    for (int f = 0; f < 5; ++f)
      kb[f] = *(const s8v*)&kvl[(f * 16 + fr) * 72 + kst * 32 + kg];
#pragma unroll
    for (int m = 0; m < 2; ++m)
#pragma unroll
      for (int f = 0; f < 5; ++f) acc[m][f] = MFMA16(pa[m], kb[f], acc[m][f]);
  }
#pragma unroll
  for (int m = 0; m < 2; ++m)
#pragma unroll
    for (int g = 0; g < 4; ++g) {
      float nrm = __shfl(acc[m][4][g], lane & 48) + 1e-6f;  // col 64 = phi_q.k_sum
      int n = w * 32 + m * 16 + (lane >> 4) * 4 + g;
      size_t orow = rowbase + n;
#pragma unroll
      for (int f = 0; f < 4; ++f)
        attno[orow * 1024 + h * 64 + f * 16 + fr] = f2bf(acc[m][f][g] / nrm);
    }
}

// ---------------------------------------------------------------- launch
extern "C" void kernel_launch(void* const* d_in, const int* in_sizes, int n_in,
                              void* d_out, int out_size, void* d_ws, size_t ws_size,
                              hipStream_t stream) {
  const float* x = (const float*)d_in[0];      // [4,4096,1024]
  const float* W_qkv = (const float*)d_in[1];  // [1024,3072]
  const float* RF = (const float*)d_in[2];     // [16,64,64]
  const float* W_out = (const float*)d_in[3];  // [1024,1024]
  const float* b_out = (const float*)d_in[4];  // [1024]
  float* out = (float*)d_out;                  // [4,4096,1024]

  char* ws = (char*)d_ws;
  size_t off = 0;
  auto alloc = [&](size_t bytes) -> void* {
    void* p = ws + off;
    off += (bytes + 255) & ~(size_t)255;
    return p;
  };
  unsigned short* xb = (unsigned short*)alloc(16384ull * 1024 * 2);
  unsigned short* wqkvt = (unsigned short*)alloc(3072ull * 1024 * 2);
  unsigned short* woutt = (unsigned short*)alloc(1024ull * 1024 * 2);
  unsigned short* rft = (unsigned short*)alloc(16ull * 64 * 64 * 2);
  unsigned short* qkv = (unsigned short*)alloc(16384ull * 3072 * 2);
  float* kvpart = (float*)alloc(64ull * 8 * 80 * 64 * 4);
  unsigned short* kvt = (unsigned short*)alloc(64ull * 80 * 64 * 2);
  unsigned short* attno = (unsigned short*)alloc(16384ull * 1024 * 2);

  cvt_bf16<<<16384, 256, 0, stream>>>(x, xb, 4194304);
  transpose_cvt<<<dim3(96, 32, 1), dim3(32, 8), 0, stream>>>(W_qkv, wqkvt, 1024, 3072);
  transpose_cvt<<<dim3(32, 32, 1), dim3(32, 8), 0, stream>>>(W_out, woutt, 1024, 1024);
  transpose_cvt<<<dim3(2, 2, 16), dim3(32, 8), 0, stream>>>(RF, rft, 64, 64);

  // qkv = xb @ wqkvt^T : M=16384 (64 tiles) x N=3072 (12 tiles), grid 768
  gemm256<0><<<768, 512, 0, stream>>>(xb, wqkvt, qkv, nullptr, 3072, 1024, 12, 96);
  phik_kv<<<dim3(8, 16, 4), 256, 0, stream>>>(qkv, rft, kvpart);
  kv_reduce<<<64, 256, 0, stream>>>(kvpart, kvt);
  phiq_out<<<dim3(32, 16, 4), 256, 0, stream>>>(qkv, rft, kvt, attno);
  // out = attno @ woutt^T + b : M=16384 x N=1024 (4 tiles), grid 256
  gemm256<1><<<256, 512, 0, stream>>>(attno, woutt, out, b_out, 1024, 1024, 4, 32);
}

// Round 3
// 229.092 us; speedup vs baseline: 1.2494x; 1.0527x over previous
//
#include <hip/hip_runtime.h>

// Performer (FAVOR+) attention, MI355X bf16-MFMA implementation.
// Round 3: fix LDS XOR swizzle to full 3 row bits (G4 recipe):
//   p ^= ((p>>7)&7)<<4   (row bits 0..2 -> 16B-chunk bits 4..6)
// R2's ((p>>8)&3)<<4 left a 4-way conflict (9.4M SQ_LDS_BANK_CONFLICT).

typedef __attribute__((ext_vector_type(8))) short s8v;   // 8 x bf16 (4 VGPR)
typedef __attribute__((ext_vector_type(4))) short s4v;   // 4 x bf16
typedef __attribute__((ext_vector_type(4))) float f4v;   // MFMA acc
typedef __attribute__((ext_vector_type(4))) int   i4v;   // 16B chunk

#define MFMA16(a, b, c) __builtin_amdgcn_mfma_f32_16x16x32_bf16((a), (b), (c), 0, 0, 0)

__device__ __forceinline__ unsigned short f2bf(float f) {
  unsigned int u = __builtin_bit_cast(unsigned int, f);
  unsigned int r = (u + 0x7FFFu + ((u >> 16) & 1u)) >> 16;  // RNE
  return (unsigned short)r;
}

__device__ __forceinline__ int swz(int p) {          // involution, bits 7..9 -> 4..6
  return p ^ (((p >> 7) & 7) << 4);
}

__device__ __forceinline__ void gl_lds16(const void* g, void* l) {
  __builtin_amdgcn_global_load_lds(
      (const __attribute__((address_space(1))) void*)g,
      (__attribute__((address_space(3))) void*)l, 16, 0, 0);
}

// ---------------------------------------------------------------- prep
__global__ __launch_bounds__(256) void cvt_bf16(const float* __restrict__ in,
                                                unsigned short* __restrict__ out,
                                                int n4) {
  int i = blockIdx.x * 256 + threadIdx.x;
  if (i >= n4) return;
  f4v v = ((const f4v*)in)[i];
  s4v o;
#pragma unroll
  for (int j = 0; j < 4; ++j) o[j] = (short)f2bf(v[j]);
  ((s4v*)out)[i] = o;
}

// out[z][c][r] = bf16(in[z][r][c]); R,C multiples of 32. block (32,8)
__global__ __launch_bounds__(256) void transpose_cvt(const float* __restrict__ in,
                                                     unsigned short* __restrict__ out,
                                                     int R, int C) {
  __shared__ float tile[32][33];
  const int tx = threadIdx.x, ty = threadIdx.y;
  const int z = blockIdx.z;
  const float* inz = in + (size_t)z * R * C;
  unsigned short* outz = out + (size_t)z * R * C;
  const int c0 = blockIdx.x * 32, r0 = blockIdx.y * 32;
#pragma unroll
  for (int j = 0; j < 4; ++j)
    tile[ty + j * 8][tx] = inz[(size_t)(r0 + ty + j * 8) * C + c0 + tx];
  __syncthreads();
#pragma unroll
  for (int j = 0; j < 4; ++j)
    outz[(size_t)(c0 + ty + j * 8) * R + r0 + tx] = f2bf(tile[tx][ty + j * 8]);
}

// ---------------------------------------------------------------- GEMM 256x256
// C[M,N] = A[M,K] @ Bt[N,K]^T.  8-phase schedule, BK=64, 512 threads (8 waves,
// 2Mx4N), 128 KiB LDS = 2 dbuf x {A,B} x 2 halves x [128 rows][64 cols] bf16.
// LDS swizzle: byte p -> p ^ (((p>>7)&7)<<4), applied as inverse-swizzled
// GLOBAL source (linear global_load_lds dest) + swizzled ds_read (rule 21).
// Phases per K-tile T: q0=(0,0) reads A-mh0+B-nh0, q1=(0,1) reads B-nh1,
// q2=(1,1) reads A-mh1, q3=(1,0) no reads. Stage half H=4T+5+q at phase q.
// Every region's last LDS read is >=2 barriers before its restage.
// vmcnt(2) at q3 guarantees tile T+1 landed before its first read.
template <int MODE>
__global__ __launch_bounds__(512, 2) void gemm256(const unsigned short* __restrict__ A,
                                                  const unsigned short* __restrict__ Bt,
                                                  void* __restrict__ Cout,
                                                  const float* __restrict__ bias,
                                                  int Nn, int K, int NTN, int CPX) {
  __shared__ __align__(128) unsigned short smem[65536];  // 128 KiB
  const int t = threadIdx.x, w = t >> 6, lane = t & 63;
  const int wm = w >> 2, wn = w & 3;
  const int fr = lane & 15, c16 = (lane >> 4) * 16;
  const int nkt = K >> 6;

  // T1: XCD-bijective block swizzle (grid % 8 == 0)
  const int bid = blockIdx.x;
  const int wg = (bid & 7) * CPX + (bid >> 3);
  const int tm = wg / NTN, tn = wg % NTN;

  const unsigned short* gA = A + (size_t)tm * 256 * K;
  const unsigned short* gB = Bt + (size_t)tn * 256 * K;

  // per-thread pre-swizzled global source offsets for the 2 staging loads
  const int s0 = swz(t * 16);
  const int s1 = swz(8192 + t * 16);
  const int goff0 = (s0 >> 7) * K + ((s0 & 127) >> 1);
  const int goff1 = ((s1 - 8192) >> 7) * K + ((s1 & 127) >> 1) + 64 * K;
  const int woff = w * 1024;  // wave-uniform LDS byte offset

  auto stage = [&](int H) {
    if (H >= nkt * 4) return;
    const int TH = H >> 2, part = H & 3;
    char* reg = (char*)smem + (((TH & 1) * 4 + part) << 14);
    const unsigned short* gp =
        (part < 2 ? gA : gB) + (size_t)((part & 1) * 128) * K + TH * 64;
    gl_lds16(gp + goff0, reg + woff);
    gl_lds16(gp + goff1, reg + 8192 + woff);
  };

  f4v acc[8][4] = {};

  // prologue: halves 0..4 (tile0 + tile1.A0), drain to 2 loads, barrier
#pragma unroll
  for (int H = 0; H < 5; ++H) stage(H);
  if (nkt > 1) { asm volatile("s_waitcnt vmcnt(2)" ::: "memory"); }
  else         { asm volatile("s_waitcnt vmcnt(0)" ::: "memory"); }
  __builtin_amdgcn_s_barrier();
  __builtin_amdgcn_sched_barrier(0);

  auto rdA = [&](int mh, s8v (&a)[4][2], const char* Ar) {
#pragma unroll
    for (int i = 0; i < 4; ++i)
#pragma unroll
      for (int ks = 0; ks < 2; ++ks) {
        int p = swz((mh * 64 + i * 16 + fr) * 128 + ks * 64 + c16);
        a[i][ks] = *(const s8v*)(Ar + p);
      }
  };
  auto rdB = [&](int nh, s8v (&b)[2][2], const char* Br, int brow) {
#pragma unroll
    for (int j = 0; j < 2; ++j)
#pragma unroll
      for (int ks = 0; ks < 2; ++ks) {
        int p = swz((brow + nh * 32 + j * 16 + fr) * 128 + ks * 64 + c16);
        b[j][ks] = *(const s8v*)(Br + p);
      }
  };
  auto mmac = [&](int mh, int nh, const s8v (&a)[4][2], const s8v (&b)[2][2]) {
    __builtin_amdgcn_s_setprio(1);
#pragma unroll
    for (int i = 0; i < 4; ++i)
#pragma unroll
      for (int j = 0; j < 2; ++j) {
        acc[mh * 4 + i][nh * 2 + j] = MFMA16(a[i][0], b[j][0], acc[mh * 4 + i][nh * 2 + j]);
        acc[mh * 4 + i][nh * 2 + j] = MFMA16(a[i][1], b[j][1], acc[mh * 4 + i][nh * 2 + j]);
      }
    __builtin_amdgcn_s_setprio(0);
  };

  const int brow = (wn & 1) * 64;
  for (int T = 0; T < nkt; ++T) {
    const int d = T & 1;
    const char* Ar = (const char*)smem + ((d * 4 + wm) << 14);
    const char* Br = (const char*)smem + ((d * 4 + 2 + (wn >> 1)) << 14);
    s8v a[4][2], b0[2][2], b1[2][2];
    // q0: quadrant (0,0)
    rdA(0, a, Ar); rdB(0, b0, Br, brow); stage(4 * T + 5);
    __builtin_amdgcn_s_barrier();
    mmac(0, 0, a, b0);
    __builtin_amdgcn_s_barrier();
    __builtin_amdgcn_sched_barrier(0);
    // q1: quadrant (0,1) — reuse A
    rdB(1, b1, Br, brow); stage(4 * T + 6);
    __builtin_amdgcn_s_barrier();
    mmac(0, 1, a, b1);
    __builtin_amdgcn_s_barrier();
    __builtin_amdgcn_sched_barrier(0);
    // q2: quadrant (1,1) — reuse B1
    rdA(1, a, Ar); stage(4 * T + 7);
    __builtin_amdgcn_s_barrier();
    mmac(1, 1, a, b1);
    __builtin_amdgcn_s_barrier();
    __builtin_amdgcn_sched_barrier(0);
    // q3: quadrant (1,0) — no reads; counted wait for tile T+1
    stage(4 * T + 8);
    if (T < nkt - 2)       { asm volatile("s_waitcnt vmcnt(2)" ::: "memory"); }
    else if (T == nkt - 2) { asm volatile("s_waitcnt vmcnt(0)" ::: "memory"); }
    __builtin_amdgcn_s_barrier();
    mmac(1, 0, a, b0);
    __builtin_amdgcn_s_barrier();
    __builtin_amdgcn_sched_barrier(0);
  }

  // epilogue
#pragma unroll
  for (int m = 0; m < 8; ++m)
#pragma unroll
    for (int n = 0; n < 4; ++n) {
      const int row = tm * 256 + wm * 128 + m * 16 + (lane >> 4) * 4;
      const int col = tn * 256 + wn * 64 + n * 16 + fr;
      if (MODE == 0) {
        unsigned short* C = (unsigned short*)Cout;
#pragma unroll
        for (int r = 0; r < 4; ++r)
          C[(size_t)(row + r) * Nn + col] = f2bf(acc[m][n][r]);
      } else {
        float* C = (float*)Cout;
        const float bv = bias[col];
#pragma unroll
        for (int r = 0; r < 4; ++r)
          C[(size_t)(row + r) * Nn + col] = acc[m][n][r] + bv;
      }
    }
}

// ---------------------------------------------------------------- phi_k + kv
// block = (och, h, b); processes 512 tokens in 4 chunks of 128.
// kvpart[bh][och][80][64]: rows 0..63 = kv^T (d,r), row 64 = k_sum, 65..79 = 0.
__global__ __launch_bounds__(256) void phik_kv(const unsigned short* __restrict__ qkv,
                                               const unsigned short* __restrict__ RFt,
                                               float* __restrict__ kvpart) {
  __shared__ unsigned short RFl[2 * 64 * 32];   // [p][r][32]
  __shared__ unsigned short Kl[2 * 128 * 32];   // [p][n][32]
  __shared__ unsigned short pht[64 * 136];      // [r][n] (+pad)
  __shared__ unsigned short vt[80 * 136];       // [d][n] (+ones row 64)
  const int t = threadIdx.x, w = t >> 6, lane = t & 63;
  const int och = blockIdx.x, h = blockIdx.y, b = blockIdx.z;
  const int fr = lane & 15, kg = (lane >> 4) * 8;

#pragma unroll
  for (int i = 0; i < 2; ++i) {  // RF[h] -> RFl
    int unit = i * 256 + w * 64 + lane;
    int p = unit >> 8, rem = unit & 255;
    int r = rem >> 2, cg = (rem & 3) * 8;
    gl_lds16(RFt + ((h * 64 + r) * 64 + p * 32 + cg), &RFl[(i * 256 + w * 64) * 8]);
  }
  for (int i = t; i < 136; i += 256) vt[64 * 136 + i] = 0x3F80;     // ones row
  for (int i = t; i < 15 * 136; i += 256) vt[65 * 136 + i] = 0;     // zero pad rows

  f4v kvacc[5] = {};

  for (int c = 0; c < 4; ++c) {
    const int n0c = och * 512 + c * 128;
    const size_t rowbase = (size_t)(b * 4096 + n0c);
#pragma unroll
    for (int i = 0; i < 4; ++i) {  // K slice -> Kl
      int unit = i * 256 + w * 64 + lane;
      int p = unit >> 9, rem = unit & 511;
      int n = rem >> 2, cg = (rem & 3) * 8;
      gl_lds16(qkv + (rowbase + n) * 3072 + 1024 + h * 64 + p * 32 + cg,
               &Kl[(i * 256 + w * 64) * 8]);
    }
    i4v vreg[4];
#pragma unroll
    for (int it = 0; it < 4; ++it) {  // V slice -> regs
      int slot = it * 256 + t;
      vreg[it] = *(const i4v*)&qkv[(rowbase + (slot >> 3)) * 3072 + 2048 + h * 64 +
                                   (slot & 7) * 8];
    }
    __syncthreads();
    // phi_k = relu(K @ RF)
    f4v pacc[2][4] = {};
#pragma unroll
    for (int p = 0; p < 2; ++p) {
      s8v ka[2], rb[4];
#pragma unroll
      for (int m = 0; m < 2; ++m)
        ka[m] = *(const s8v*)&Kl[p * 4096 + (w * 32 + m * 16 + fr) * 32 + kg];
#pragma unroll
      for (int rf = 0; rf < 4; ++rf)
        rb[rf] = *(const s8v*)&RFl[p * 2048 + (rf * 16 + fr) * 32 + kg];
#pragma unroll
      for (int m = 0; m < 2; ++m)
#pragma unroll
        for (int rf = 0; rf < 4; ++rf)
          pacc[m][rf] = MFMA16(ka[m], rb[rf], pacc[m][rf]);
    }
    // v -> vt (transposed)
#pragma unroll
    for (int it = 0; it < 4; ++it) {
      int slot = it * 256 + t;
      int vn = slot >> 3, vdh = (slot & 7) * 8;
      const unsigned short* vr = (const unsigned short*)&vreg[it];
#pragma unroll
      for (int j = 0; j < 8; ++j) vt[(vdh + j) * 136 + vn] = vr[j];
    }
    // phi -> pht (transposed, relu, bf16)
#pragma unroll
    for (int m = 0; m < 2; ++m)
#pragma unroll
      for (int rf = 0; rf < 4; ++rf) {
        int r = rf * 16 + fr;
        int nb = w * 32 + m * 16 + (lane >> 4) * 4;
        s4v pk;
#pragma unroll
        for (int g = 0; g < 4; ++g) pk[g] = (short)f2bf(fmaxf(pacc[m][rf][g], 0.0f));
        *(s4v*)&pht[r * 136 + nb] = pk;
      }
    __syncthreads();
    // kv_aug[d][r] += vt @ pht^T  (wave w owns r-cols w*16..+15)
#pragma unroll
    for (int kst = 0; kst < 4; ++kst) {
      s8v pb = *(const s8v*)&pht[(w * 16 + fr) * 136 + kst * 32 + kg];
#pragma unroll
      for (int f = 0; f < 5; ++f) {
        s8v va = *(const s8v*)&vt[(f * 16 + fr) * 136 + kst * 32 + kg];
        kvacc[f] = MFMA16(va, pb, kvacc[f]);
      }
    }
  }
  const int bh = b * 16 + h;
  float* outp = kvpart + ((size_t)bh * 8 + och) * (80 * 64);
#pragma unroll
  for (int f = 0; f < 5; ++f) {
    int row = f * 16 + (lane >> 4) * 4;
    int col = w * 16 + fr;
#pragma unroll
    for (int g = 0; g < 4; ++g) outp[(row + g) * 64 + col] = kvacc[f][g];
  }
}

__global__ __launch_bounds__(256) void kv_reduce(const float* __restrict__ kvpart,
                                                 unsigned short* __restrict__ kvt) {
  const int bh = blockIdx.x, t = threadIdx.x;
  for (int i = t; i < 80 * 64; i += 256) {
    float s = 0.f;
#pragma unroll
    for (int c = 0; c < 8; ++c) s += kvpart[((size_t)bh * 8 + c) * 5120 + i];
    kvt[(size_t)bh * 5120 + i] = f2bf(s);
  }
}

// ---------------------------------------------------------------- phi_q + out
// block = (ch, h, b); 128 tokens. attno[token][h*64+d] = (phi_q@kv)/(phi_q.k_sum+eps)
__global__ __launch_bounds__(256) void phiq_out(const unsigned short* __restrict__ qkv,
                                                const unsigned short* __restrict__ RFt,
                                                const unsigned short* __restrict__ kvt,
                                                unsigned short* __restrict__ attno) {
  __shared__ unsigned short RFl[2 * 64 * 32];  // [p][r][32]
  __shared__ unsigned short Ql[2 * 128 * 32];  // [p][n][32]
  __shared__ unsigned short phl[128 * 72];     // [n][r] (+pad)
  __shared__ unsigned short kvl[80 * 72];      // [d][r] (+pad), row 64 = k_sum
  const int t = threadIdx.x, w = t >> 6, lane = t & 63;
  const int ch = blockIdx.x, h = blockIdx.y, b = blockIdx.z;
  const int fr = lane & 15, kg = (lane >> 4) * 8;
  const int bh = b * 16 + h;
  const size_t rowbase = (size_t)(b * 4096 + ch * 128);

#pragma unroll
  for (int i = 0; i < 2; ++i) {
    int unit = i * 256 + w * 64 + lane;
    int p = unit >> 8, rem = unit & 255;
    int r = rem >> 2, cg = (rem & 3) * 8;
    gl_lds16(RFt + ((h * 64 + r) * 64 + p * 32 + cg), &RFl[(i * 256 + w * 64) * 8]);
  }
#pragma unroll
  for (int i = 0; i < 4; ++i) {
    int unit = i * 256 + w * 64 + lane;
    int p = unit >> 9, rem = unit & 511;
    int n = rem >> 2, cg = (rem & 3) * 8;
    gl_lds16(qkv + (rowbase + n) * 3072 + h * 64 + p * 32 + cg,
             &Ql[(i * 256 + w * 64) * 8]);
  }
  for (int i = t; i < 640; i += 256) {  // kvt -> kvl (pad 64->72)
    int row = i >> 3, cg = (i & 7) * 8;
    *(i4v*)&kvl[row * 72 + cg] = *(const i4v*)&kvt[(size_t)bh * 5120 + row * 64 + cg];
  }
  __syncthreads();
  f4v pacc[2][4] = {};
#pragma unroll
  for (int p = 0; p < 2; ++p) {
    s8v qa[2], rb[4];
#pragma unroll
    for (int m = 0; m < 2; ++m)
      qa[m] = *(const s8v*)&Ql[p * 4096 + (w * 32 + m * 16 + fr) * 32 + kg];
#pragma unroll
    for (int rf = 0; rf < 4; ++rf)
      rb[rf] = *(const s8v*)&RFl[p * 2048 + (rf * 16 + fr) * 32 + kg];
#pragma unroll
    for (int m = 0; m < 2; ++m)
#pragma unroll
      for (int rf = 0; rf < 4; ++rf)
        pacc[m][rf] = MFMA16(qa[m], rb[rf], pacc[m][rf]);
  }
#pragma unroll
  for (int m = 0; m < 2; ++m)
#pragma unroll
    for (int rf = 0; rf < 4; ++rf) {
      int r = rf * 16 + fr;
      int nb = w * 32 + m * 16 + (lane >> 4) * 4;
#pragma unroll
      for (int g = 0; g < 4; ++g)
        phl[(nb + g) * 72 + r] = f2bf(fmaxf(pacc[m][rf][g], 0.0f));
    }
  __syncthreads();
  f4v acc[2][5] = {};
#pragma unroll
  for (int kst = 0; kst < 2; ++kst) {
    s8v pa[2], kb[5];
#pragma unroll
    for (int m = 0; m < 2; ++m)
      pa[m] = *(const s8v*)&phl[(w * 32 + m * 16 + fr) * 72 + kst * 32 + kg];
#pragma unroll
    for (int f = 0; f < 5; ++f)
      kb[f] = *(const s8v*)&kvl[(f * 16 + fr) * 72 + kst * 32 + kg];
#pragma unroll
    for (int m = 0; m < 2; ++m)
#pragma unroll
      for (int f = 0; f < 5; ++f) acc[m][f] = MFMA16(pa[m], kb[f], acc[m][f]);
  }
#pragma unroll
  for (int m = 0; m < 2; ++m)
#pragma unroll
    for (int g = 0; g < 4; ++g) {
      float nrm = __shfl(acc[m][4][g], lane & 48) + 1e-6f;  // col 64 = phi_q.k_sum
      int n = w * 32 + m * 16 + (lane >> 4) * 4 + g;
      size_t orow = rowbase + n;
#pragma unroll
      for (int f = 0; f < 4; ++f)
        attno[orow * 1024 + h * 64 + f * 16 + fr] = f2bf(acc[m][f][g] / nrm);
    }
}

// ---------------------------------------------------------------- launch
extern "C" void kernel_launch(void* const* d_in, const int* in_sizes, int n_in,
                              void* d_out, int out_size, void* d_ws, size_t ws_size,
                              hipStream_t stream) {
  const float* x = (const float*)d_in[0];      // [4,4096,1024]
  const float* W_qkv = (const float*)d_in[1];  // [1024,3072]
  const float* RF = (const float*)d_in[2];     // [16,64,64]
  const float* W_out = (const float*)d_in[3];  // [1024,1024]
  const float* b_out = (const float*)d_in[4];  // [1024]
  float* out = (float*)d_out;                  // [4,4096,1024]

  char* ws = (char*)d_ws;
  size_t off = 0;
  auto alloc = [&](size_t bytes) -> void* {
    void* p = ws + off;
    off += (bytes + 255) & ~(size_t)255;
    return p;
  };
  unsigned short* xb = (unsigned short*)alloc(16384ull * 1024 * 2);
  unsigned short* wqkvt = (unsigned short*)alloc(3072ull * 1024 * 2);
  unsigned short* woutt = (unsigned short*)alloc(1024ull * 1024 * 2);
  unsigned short* rft = (unsigned short*)alloc(16ull * 64 * 64 * 2);
  unsigned short* qkv = (unsigned short*)alloc(16384ull * 3072 * 2);
  float* kvpart = (float*)alloc(64ull * 8 * 80 * 64 * 4);
  unsigned short* kvt = (unsigned short*)alloc(64ull * 80 * 64 * 2);
  unsigned short* attno = (unsigned short*)alloc(16384ull * 1024 * 2);

  cvt_bf16<<<16384, 256, 0, stream>>>(x, xb, 4194304);
  transpose_cvt<<<dim3(96, 32, 1), dim3(32, 8), 0, stream>>>(W_qkv, wqkvt, 1024, 3072);
  transpose_cvt<<<dim3(32, 32, 1), dim3(32, 8), 0, stream>>>(W_out, woutt, 1024, 1024);
  transpose_cvt<<<dim3(2, 2, 16), dim3(32, 8), 0, stream>>>(RF, rft, 64, 64);

  // qkv = xb @ wqkvt^T : M=16384 (64 tiles) x N=3072 (12 tiles), grid 768
  gemm256<0><<<768, 512, 0, stream>>>(xb, wqkvt, qkv, nullptr, 3072, 1024, 12, 96);
  phik_kv<<<dim3(8, 16, 4), 256, 0, stream>>>(qkv, rft, kvpart);
  kv_reduce<<<64, 256, 0, stream>>>(kvpart, kvt);
  phiq_out<<<dim3(32, 16, 4), 256, 0, stream>>>(qkv, rft, kvt, attno);
  // out = attno @ woutt^T + b : M=16384 x N=1024 (4 tiles), grid 256
  gemm256<1><<<256, 512, 0, stream>>>(attno, woutt, out, b_out, 1024, 1024, 4, 32);
}